// Round 2
// baseline (138.751 us; speedup 1.0000x reference)
//
#include <hip/hip_runtime.h>
#include <cstdint>

#define MDIM 2048
#define KDIM 1024
#define CDIM 8192
#define BM 256
#define BN 256
#define BK 32
#define NT (KDIM / BK)      // 32 K-tiles
#define NCHUNK (CDIM / 64)  // 128 chunks of 64 cols

typedef __attribute__((ext_vector_type(8))) __bf16 bf16x8;
typedef __attribute__((ext_vector_type(4))) float f32x4;

// ---------- helpers ----------
__device__ __forceinline__ unsigned short f2bf(float f) {
  unsigned u = __float_as_uint(f);
  u += 0x7fffu + ((u >> 16) & 1u);   // RNE
  return (unsigned short)(u >> 16);
}

__device__ __forceinline__ void async_ld16(const void* g, void* l) {
  __builtin_amdgcn_global_load_lds(
      (__attribute__((address_space(1))) void*)(g),
      (__attribute__((address_space(3))) void*)(l),
      16, 0, 0);
}

// ---------- K0: fused convert x & centroids to bf16; c2 = ||c||^2 ----------
__global__ __launch_bounds__(256) void convert_all(const float* __restrict__ x,
                                                   const float* __restrict__ cent,
                                                   unsigned short* __restrict__ xb,
                                                   unsigned short* __restrict__ cb,
                                                   float* __restrict__ c2) {
  const int b = blockIdx.x, t = threadIdx.x;
  if (b < MDIM) {
    const float4 v = ((const float4*)(x + (size_t)b * KDIM))[t];
    ushort4 o;
    o.x = f2bf(v.x); o.y = f2bf(v.y); o.z = f2bf(v.z); o.w = f2bf(v.w);
    ((ushort4*)(xb + (size_t)b * KDIM))[t] = o;
  } else {
    const int row = b - MDIM;
    const float4 v = ((const float4*)(cent + (size_t)row * KDIM))[t];
    ushort4 o;
    o.x = f2bf(v.x); o.y = f2bf(v.y); o.z = f2bf(v.z); o.w = f2bf(v.w);
    ((ushort4*)(cb + (size_t)row * KDIM))[t] = o;
    float p = v.x * v.x + v.y * v.y + v.z * v.z + v.w * v.w;
    for (int d = 32; d; d >>= 1) p += __shfl_down(p, d, 64);
    __shared__ float red[4];
    if ((t & 63) == 0) red[t >> 6] = p;
    __syncthreads();
    if (t == 0) c2[row] = red[0] + red[1] + red[2] + red[3];
  }
}

// ---------- K1: 256x256-tile bf16 MFMA GEMM, 4-slot LDS ring, 2-phase/tile (T3) ----------
// s = 2*x.c - c2, fused per-64col online softmax/argmax epilogue.
// 8 waves (2M x 4N), per-wave output 128x64. LDS ring: 4 slots x (A 16KB + B 16KB).
// Phase density matches the verified 8-phase template: 2 barriers/phase,
// 16 MFMA/phase, 2 global_load_lds/phase, counted vmcnt only at tile boundary.
__global__ __launch_bounds__(512, 2) void gemm_reduce(
    const unsigned short* __restrict__ Ab, const unsigned short* __restrict__ Bb,
    const float* __restrict__ c2,
    float* __restrict__ pm, float* __restrict__ pl, int* __restrict__ pidx) {
  __shared__ __align__(16) char lds[4 * 32768];   // 128 KB

  const int tid = threadIdx.x;
  const int wave = tid >> 6, lane = tid & 63;
  const int wm = wave >> 2, wn = wave & 3;        // 2 x 4 wave grid
  const int quad = lane >> 4, c16 = lane & 15;

  // XCD-chunked block remap: XCD k owns bm=k (A-panel 512KB -> L2-resident)
  const int id = blockIdx.y * gridDim.x + blockIdx.x;      // 0..255
  const int lid = (id & 7) * 32 + (id >> 3);               // bijective, 256%8==0
  const int bm = lid >> 5, bn = lid & 31;
  const int bmBase = bm * BM, bnBase = bn * BN;

  // ---- staging addresses: thread stages 2 A-chunks + 2 B-chunks (16B each) per tile ----
  // LDS chunk i (i = tid, tid+512) holds logical chunk (row = i>>2, c ^ s(row)),
  // s(row) = (row>>1)&3  -> conflict-free swizzle; LDS dest stays linear (rule #21).
  const int r1 = tid >> 2, c1 = (tid & 3) ^ ((r1 >> 1) & 3);
  const int r2 = (tid + 512) >> 2, c2s = (tid & 3) ^ ((r2 >> 1) & 3);
  const char* Ag1 = (const char*)(Ab + (size_t)(bmBase + r1) * KDIM + c1 * 8);
  const char* Ag2 = (const char*)(Ab + (size_t)(bmBase + r2) * KDIM + c2s * 8);
  const char* Bg1 = (const char*)(Bb + (size_t)(bnBase + r1) * KDIM + c1 * 8);
  const char* Bg2 = (const char*)(Bb + (size_t)(bnBase + r2) * KDIM + c2s * 8);
  const int wbyte = wave * 1024;                  // wave-uniform LDS base (lane*16 implicit)

  // ---- fragment read offsets (swizzled): logical (row, quad) lives at chunk quad^s(row) ----
  int aoff[8], boff[4];
#pragma unroll
  for (int mt = 0; mt < 8; ++mt) {
    const int row = wm * 128 + mt * 16 + c16;
    aoff[mt] = row * 64 + ((quad ^ ((row >> 1) & 3)) * 16);
  }
#pragma unroll
  for (int nt = 0; nt < 4; ++nt) {
    const int col = wn * 64 + nt * 16 + c16;
    boff[nt] = col * 64 + ((quad ^ ((col >> 1) & 3)) * 16);
  }

  f32x4 acc[8][4] = {};

#define STAGE_FULL(T)                                     \
  {                                                       \
    const int _ko = (T) * (BK * 2);                       \
    char* _sb = &lds[((T) & 3) * 32768];                  \
    async_ld16(Ag1 + _ko, _sb + wbyte);                   \
    async_ld16(Ag2 + _ko, _sb + 8192 + wbyte);            \
    async_ld16(Bg1 + _ko, _sb + 16384 + wbyte);           \
    async_ld16(Bg2 + _ko, _sb + 24576 + wbyte);           \
  }

  // prologue: 3 tiles in flight (12 loads/wave); gate tile 0 (retire oldest 4)
  STAGE_FULL(0); STAGE_FULL(1); STAGE_FULL(2);
  asm volatile("s_waitcnt vmcnt(8)" ::: "memory");
  __builtin_amdgcn_s_barrier();
  __builtin_amdgcn_sched_barrier(0);

#pragma unroll 1
  for (int t = 0; t < NT; ++t) {
    const char* sb = &lds[(t & 3) * 32768];
    bf16x8 a0[4], a1[4], b[4];

    // ======== phase 0: A-lo + B reads | stage A-half(t+3) | 16 MFMA ========
#pragma unroll
    for (int mt = 0; mt < 4; ++mt) a0[mt] = *(const bf16x8*)(sb + aoff[mt]);
#pragma unroll
    for (int nt = 0; nt < 4; ++nt) b[nt] = *(const bf16x8*)(sb + 16384 + boff[nt]);
    if (t < NT - 3) {
      const int ko = (t + 3) * (BK * 2);
      char* db = &lds[((t + 3) & 3) * 32768];   // slot (t-1)&3: freed at tile-t entry barrier
      async_ld16(Ag1 + ko, db + wbyte);
      async_ld16(Ag2 + ko, db + 8192 + wbyte);
    }
    __builtin_amdgcn_s_barrier();
    asm volatile("s_waitcnt lgkmcnt(0)" ::: "memory");
    __builtin_amdgcn_sched_barrier(0);
    __builtin_amdgcn_s_setprio(1);
#pragma unroll
    for (int mt = 0; mt < 4; ++mt)
#pragma unroll
      for (int nt = 0; nt < 4; ++nt)
        acc[mt][nt] = __builtin_amdgcn_mfma_f32_16x16x32_bf16(a0[mt], b[nt], acc[mt][nt], 0, 0, 0);
    __builtin_amdgcn_s_setprio(0);
    __builtin_amdgcn_s_barrier();
    __builtin_amdgcn_sched_barrier(0);

    // ======== phase 1: A-hi reads | stage B-half(t+3) | 16 MFMA ========
#pragma unroll
    for (int mt = 0; mt < 4; ++mt) a1[mt] = *(const bf16x8*)(sb + aoff[4 + mt]);
    if (t < NT - 3) {
      const int ko = (t + 3) * (BK * 2);
      char* db = &lds[((t + 3) & 3) * 32768];
      async_ld16(Bg1 + ko, db + 16384 + wbyte);
      async_ld16(Bg2 + ko, db + 24576 + wbyte);
    }
    __builtin_amdgcn_s_barrier();
    asm volatile("s_waitcnt lgkmcnt(0)" ::: "memory");
    __builtin_amdgcn_sched_barrier(0);
    __builtin_amdgcn_s_setprio(1);
#pragma unroll
    for (int mt = 0; mt < 4; ++mt)
#pragma unroll
      for (int nt = 0; nt < 4; ++nt)
        acc[4 + mt][nt] = __builtin_amdgcn_mfma_f32_16x16x32_bf16(a1[mt], b[nt], acc[4 + mt][nt], 0, 0, 0);
    __builtin_amdgcn_s_setprio(0);

    // ---- tile boundary: counted gate for slot t+1 (never 0 until tail) ----
    if (t < NT - 1) {
      if (t <= NT - 4)      asm volatile("s_waitcnt vmcnt(8)" ::: "memory");
      else if (t == NT - 3) asm volatile("s_waitcnt vmcnt(4)" ::: "memory");
      else                  asm volatile("s_waitcnt vmcnt(0)" ::: "memory");
      __builtin_amdgcn_s_barrier();
      __builtin_amdgcn_sched_barrier(0);
    }
  }
#undef STAGE_FULL

  // Epilogue: C/D layout: col = lane&15, row = quad*4 + reg (verified convention).
  const int colbase = bnBase + wn * 64;
  float c2v[4];
#pragma unroll
  for (int nt = 0; nt < 4; ++nt) c2v[nt] = c2[colbase + nt * 16 + c16];

  const int chunk = bn * 4 + wn;
#pragma unroll
  for (int mt = 0; mt < 8; ++mt) {
#pragma unroll
    for (int r = 0; r < 4; ++r) {
      float sv[4];
#pragma unroll
      for (int nt = 0; nt < 4; ++nt) sv[nt] = 2.0f * acc[mt][nt][r] - c2v[nt];
      float m = sv[0];
      int idx = colbase + c16;
#pragma unroll
      for (int nt = 1; nt < 4; ++nt) {
        if (sv[nt] > m) { m = sv[nt]; idx = colbase + nt * 16 + c16; }
      }
      float l = 0.f;
#pragma unroll
      for (int nt = 0; nt < 4; ++nt) l += __expf(sv[nt] - m);
      for (int d = 1; d < 16; d <<= 1) {
        float om = __shfl_xor(m, d, 64);
        float ol = __shfl_xor(l, d, 64);
        int oi = __shfl_xor(idx, d, 64);
        float M = fmaxf(m, om);
        l = l * __expf(m - M) + ol * __expf(om - M);
        idx = (om > m || (om == m && oi < idx)) ? oi : idx;
        m = M;
      }
      if (c16 == 0) {
        const int row = bmBase + wm * 128 + mt * 16 + quad * 4 + r;
        pm[(size_t)row * NCHUNK + chunk] = m;
        pl[(size_t)row * NCHUNK + chunk] = l;
        pidx[(size_t)row * NCHUNK + chunk] = idx;
      }
    }
  }
}

// ---------- K2: per-row combine (128 threads = 128 chunks) + fused sy dot ----------
__global__ __launch_bounds__(128) void combine_kernel(
    const float* __restrict__ pm, const float* __restrict__ pl,
    const int* __restrict__ pidx, const float* __restrict__ x,
    const float* __restrict__ cent, const float* __restrict__ c2,
    const int* __restrict__ y,
    float* __restrict__ loss_part, float* __restrict__ corr_part) {
  const int row = blockIdx.x, t = threadIdx.x;  // t = chunk id, 0..127
  const int yc = y[row];

  float m = pm[(size_t)row * NCHUNK + t];
  float l = pl[(size_t)row * NCHUNK + t];
  int idx = pidx[(size_t)row * NCHUNK + t];

  // fp32 partial dot: 8 elements per thread
  const float4* xa = (const float4*)(x + (size_t)row * KDIM) + t * 2;
  const float4* ca = (const float4*)(cent + (size_t)yc * KDIM) + t * 2;
  const float4 a0 = xa[0], a1 = xa[1], b0 = ca[0], b1 = ca[1];
  float dot = a0.x * b0.x + a0.y * b0.y + a0.z * b0.z + a0.w * b0.w
            + a1.x * b1.x + a1.y * b1.y + a1.z * b1.z + a1.w * b1.w;

  for (int d = 1; d < 64; d <<= 1) {
    const float om = __shfl_xor(m, d, 64);
    const float ol = __shfl_xor(l, d, 64);
    const int oi = __shfl_xor(idx, d, 64);
    const float od = __shfl_xor(dot, d, 64);
    const float M = fmaxf(m, om);
    l = l * __expf(m - M) + ol * __expf(om - M);
    idx = (om > m || (om == m && oi < idx)) ? oi : idx;
    m = M;
    dot += od;
  }
  __shared__ float sm[2], sl[2], sd[2];
  __shared__ int si[2];
  if ((t & 63) == 0) { sm[t >> 6] = m; sl[t >> 6] = l; si[t >> 6] = idx; sd[t >> 6] = dot; }
  __syncthreads();
  if (t == 0) {
    const float m0 = sm[0], m1 = sm[1];
    const float M = fmaxf(m0, m1);
    const float L = sl[0] * __expf(m0 - M) + sl[1] * __expf(m1 - M);
    int g;
    if (m1 > m0 || (m1 == m0 && si[1] < si[0])) g = si[1]; else g = si[0];
    const float sy = 2.0f * (sd[0] + sd[1]) - c2[yc];
    loss_part[row] = __logf(L) + M - sy;
    corr_part[row] = (g == yc) ? 1.f : 0.f;
  }
}

// ---------- K3: finalize means ----------
__global__ __launch_bounds__(256) void finalize(const float* __restrict__ loss_part,
                                                const float* __restrict__ corr_part,
                                                float* __restrict__ out) {
  const int t = threadIdx.x;
  float s0 = 0.f, s1 = 0.f;
  for (int i = t; i < MDIM; i += 256) { s0 += loss_part[i]; s1 += corr_part[i]; }
  for (int d = 32; d; d >>= 1) {
    s0 += __shfl_down(s0, d, 64);
    s1 += __shfl_down(s1, d, 64);
  }
  __shared__ float r0[4], r1[4];
  if ((t & 63) == 0) { r0[t >> 6] = s0; r1[t >> 6] = s1; }
  __syncthreads();
  if (t == 0) {
    out[0] = (r0[0] + r0[1] + r0[2] + r0[3]) * (1.0f / MDIM);
    out[1] = (r1[0] + r1[1] + r1[2] + r1[3]) * (1.0f / MDIM);
  }
}

// ---------- launch ----------
extern "C" void kernel_launch(void* const* d_in, const int* in_sizes, int n_in,
                              void* d_out, int out_size, void* d_ws, size_t ws_size,
                              hipStream_t stream) {
  const float* x = (const float*)d_in[0];
  const int* y = (const int*)d_in[1];
  const float* cent = (const float*)d_in[2];
  float* out = (float*)d_out;

  char* ws = (char*)d_ws;
  const size_t OFF_XB = 0;                                   // 4 MB
  const size_t OFF_CB = OFF_XB + (size_t)MDIM * KDIM * 2;    // 16 MB
  const size_t OFF_C2 = OFF_CB + (size_t)CDIM * KDIM * 2;    // 32 KB
  const size_t OFF_PM = OFF_C2 + (size_t)CDIM * 4;           // 1 MB
  const size_t OFF_PL = OFF_PM + (size_t)NCHUNK * MDIM * 4;  // 1 MB
  const size_t OFF_PI = OFF_PL + (size_t)NCHUNK * MDIM * 4;  // 1 MB
  const size_t OFF_LP = OFF_PI + (size_t)NCHUNK * MDIM * 4;  // 8 KB
  const size_t OFF_CP = OFF_LP + (size_t)MDIM * 4;           // 8 KB
  const size_t NEED = OFF_CP + (size_t)MDIM * 4;
  if (ws_size < NEED) return;

  unsigned short* xb = (unsigned short*)(ws + OFF_XB);
  unsigned short* cb = (unsigned short*)(ws + OFF_CB);
  float* c2 = (float*)(ws + OFF_C2);
  float* pm = (float*)(ws + OFF_PM);
  float* pl = (float*)(ws + OFF_PL);
  int* pidx = (int*)(ws + OFF_PI);
  float* loss_part = (float*)(ws + OFF_LP);
  float* corr_part = (float*)(ws + OFF_CP);

  convert_all<<<MDIM + CDIM, 256, 0, stream>>>(x, cent, xb, cb, c2);
  gemm_reduce<<<dim3(CDIM / BN, MDIM / BM), 512, 0, stream>>>(xb, cb, c2, pm, pl, pidx);
  combine_kernel<<<MDIM, 128, 0, stream>>>(pm, pl, pidx, x, cent, c2, y, loss_part, corr_part);
  finalize<<<1, 256, 0, stream>>>(loss_part, corr_part, out);
}

// Round 3
// 135.838 us; speedup vs baseline: 1.0214x; 1.0214x over previous
//
#include <hip/hip_runtime.h>
#include <cstdint>

#define MDIM 2048
#define KDIM 1024
#define CDIM 8192
#define BM 256
#define BN 256
#define BK 32
#define NT (KDIM / BK)      // 32 K-tiles
#define NCHUNK (CDIM / 64)  // 128 chunks of 64 cols

typedef __attribute__((ext_vector_type(8))) __bf16 bf16x8;
typedef __attribute__((ext_vector_type(4))) float f32x4;

// ---------- helpers ----------
__device__ __forceinline__ unsigned short f2bf(float f) {
  unsigned u = __float_as_uint(f);
  u += 0x7fffu + ((u >> 16) & 1u);   // RNE
  return (unsigned short)(u >> 16);
}

__device__ __forceinline__ void async_ld16(const void* g, void* l) {
  __builtin_amdgcn_global_load_lds(
      (__attribute__((address_space(1))) void*)(g),
      (__attribute__((address_space(3))) void*)(l),
      16, 0, 0);
}

// ---------- K0: fused convert x & centroids to bf16; c2 = ||c||^2 ----------
__global__ __launch_bounds__(256) void convert_all(const float* __restrict__ x,
                                                   const float* __restrict__ cent,
                                                   unsigned short* __restrict__ xb,
                                                   unsigned short* __restrict__ cb,
                                                   float* __restrict__ c2) {
  const int b = blockIdx.x, t = threadIdx.x;
  if (b < MDIM) {
    const float4 v = ((const float4*)(x + (size_t)b * KDIM))[t];
    ushort4 o;
    o.x = f2bf(v.x); o.y = f2bf(v.y); o.z = f2bf(v.z); o.w = f2bf(v.w);
    ((ushort4*)(xb + (size_t)b * KDIM))[t] = o;
  } else {
    const int row = b - MDIM;
    const float4 v = ((const float4*)(cent + (size_t)row * KDIM))[t];
    ushort4 o;
    o.x = f2bf(v.x); o.y = f2bf(v.y); o.z = f2bf(v.z); o.w = f2bf(v.w);
    ((ushort4*)(cb + (size_t)row * KDIM))[t] = o;
    float p = v.x * v.x + v.y * v.y + v.z * v.z + v.w * v.w;
    for (int d = 32; d; d >>= 1) p += __shfl_down(p, d, 64);
    __shared__ float red[4];
    if ((t & 63) == 0) red[t >> 6] = p;
    __syncthreads();
    if (t == 0) c2[row] = red[0] + red[1] + red[2] + red[3];
  }
}

// ---------- K1: 256x256-tile bf16 MFMA GEMM, 4-slot LDS ring ----------
// 2 K-tiles per barrier pair: entry gate vmcnt(4) lands BOTH tiles; the odd tile's
// reads + 48 MFMAs run barrier-free, overlapping via split lgkmcnt waits.
// s = 2*x.c - c2, fused per-64col online softmax/argmax epilogue.
__global__ __launch_bounds__(512, 2) void gemm_reduce(
    const unsigned short* __restrict__ Ab, const unsigned short* __restrict__ Bb,
    const float* __restrict__ c2,
    float* __restrict__ pm, float* __restrict__ pl, int* __restrict__ pidx) {
  __shared__ __align__(16) char lds[4 * 32768];   // 128 KB

  const int tid = threadIdx.x;
  const int wave = tid >> 6, lane = tid & 63;
  const int wm = wave >> 2, wn = wave & 3;        // 2 x 4 wave grid
  const int quad = lane >> 4, c16 = lane & 15;

  // XCD-chunked block remap: XCD k owns bm=k (A-panel 512KB -> L2-resident)
  const int id = blockIdx.y * gridDim.x + blockIdx.x;      // 0..255
  const int lid = (id & 7) * 32 + (id >> 3);               // bijective, 256%8==0
  const int bm = lid >> 5, bn = lid & 31;
  const int bmBase = bm * BM, bnBase = bn * BN;

  // ---- staging addresses: thread stages 2 A-chunks + 2 B-chunks (16B each) per tile ----
  // LDS chunk i (i = tid, tid+512) holds logical chunk (row = i>>2, c ^ s(row)),
  // s(row) = (row>>1)&3  -> conflict-free swizzle; LDS dest stays linear (rule #21).
  const int r1 = tid >> 2, c1 = (tid & 3) ^ ((r1 >> 1) & 3);
  const int r2 = (tid + 512) >> 2, c2s = (tid & 3) ^ ((r2 >> 1) & 3);
  const char* Ag1 = (const char*)(Ab + (size_t)(bmBase + r1) * KDIM + c1 * 8);
  const char* Ag2 = (const char*)(Ab + (size_t)(bmBase + r2) * KDIM + c2s * 8);
  const char* Bg1 = (const char*)(Bb + (size_t)(bnBase + r1) * KDIM + c1 * 8);
  const char* Bg2 = (const char*)(Bb + (size_t)(bnBase + r2) * KDIM + c2s * 8);
  const int wbyte = wave * 1024;                  // wave-uniform LDS base (lane*16 implicit)

  // ---- fragment read offsets (swizzled): logical (row, quad) lives at chunk quad^s(row) ----
  int aoff[8], boff[4];
#pragma unroll
  for (int mt = 0; mt < 8; ++mt) {
    const int row = wm * 128 + mt * 16 + c16;
    aoff[mt] = row * 64 + ((quad ^ ((row >> 1) & 3)) * 16);
  }
#pragma unroll
  for (int nt = 0; nt < 4; ++nt) {
    const int col = wn * 64 + nt * 16 + c16;
    boff[nt] = col * 64 + ((quad ^ ((col >> 1) & 3)) * 16);
  }

  f32x4 acc[8][4] = {};

#define STAGE(T)                                          \
  {                                                       \
    const int _ko = (T) * (BK * 2);                       \
    char* _sb = &lds[((T) & 3) * 32768];                  \
    async_ld16(Ag1 + _ko, _sb + wbyte);                   \
    async_ld16(Ag2 + _ko, _sb + 8192 + wbyte);            \
    async_ld16(Bg1 + _ko, _sb + 16384 + wbyte);           \
    async_ld16(Bg2 + _ko, _sb + 24576 + wbyte);           \
  }

  // prologue: 3 tiles in flight (12 loads/wave)
  STAGE(0); STAGE(1); STAGE(2);

#pragma unroll 1
  for (int i = 0; i < NT / 2; ++i) {
    const int t0 = 2 * i;
    const char* sbE = &lds[(t0 & 3) * 32768];
    const char* sbO = &lds[((t0 + 1) & 3) * 32768];

    // ---- entry gate: tiles t0 AND t0+1 landed (only t0+2's 4 loads may fly) ----
    if (i == NT / 2 - 1) asm volatile("s_waitcnt vmcnt(0)" ::: "memory");
    else                 asm volatile("s_waitcnt vmcnt(4)" ::: "memory");
    __builtin_amdgcn_s_barrier();
    __builtin_amdgcn_sched_barrier(0);

    bf16x8 aE[8], bE[4], aO[8], bO[4];
    // even-tile reads: first 8 issued = a0-3 + b0-3, then a4-7
#pragma unroll
    for (int mt = 0; mt < 4; ++mt) aE[mt] = *(const bf16x8*)(sbE + aoff[mt]);
#pragma unroll
    for (int nt = 0; nt < 4; ++nt) bE[nt] = *(const bf16x8*)(sbE + 16384 + boff[nt]);
#pragma unroll
    for (int mt = 4; mt < 8; ++mt) aE[mt] = *(const bf16x8*)(sbE + aoff[mt]);
    if (t0 + 3 < NT) STAGE(t0 + 3);   // slot (t0-1)&3: freed by entry barrier
    asm volatile("s_waitcnt lgkmcnt(4)" ::: "memory");   // a0-3 + b ready; a4-7 drain under MFMA
    __builtin_amdgcn_sched_barrier(0);
    __builtin_amdgcn_s_setprio(1);
#pragma unroll
    for (int mt = 0; mt < 4; ++mt)
#pragma unroll
      for (int nt = 0; nt < 4; ++nt)
        acc[mt][nt] = __builtin_amdgcn_mfma_f32_16x16x32_bf16(aE[mt], bE[nt], acc[mt][nt], 0, 0, 0);
    __builtin_amdgcn_s_setprio(0);
    asm volatile("s_waitcnt lgkmcnt(0)" ::: "memory");   // all even-slot reads retired
    __builtin_amdgcn_sched_barrier(0);
    __builtin_amdgcn_s_barrier();                        // even slot free for restage

    // ---- barrier-free window: odd reads + stage + 48 MFMAs ----
#pragma unroll
    for (int mt = 0; mt < 4; ++mt) aO[mt] = *(const bf16x8*)(sbO + aoff[mt]);
#pragma unroll
    for (int nt = 0; nt < 4; ++nt) bO[nt] = *(const bf16x8*)(sbO + 16384 + boff[nt]);
    if (t0 + 4 < NT) STAGE(t0 + 4);   // even slot: freed by mid barrier
    __builtin_amdgcn_sched_barrier(0);
    __builtin_amdgcn_s_setprio(1);
#pragma unroll
    for (int mt = 4; mt < 8; ++mt)
#pragma unroll
      for (int nt = 0; nt < 4; ++nt)
        acc[mt][nt] = __builtin_amdgcn_mfma_f32_16x16x32_bf16(aE[mt], bE[nt], acc[mt][nt], 0, 0, 0);
    __builtin_amdgcn_s_setprio(0);
#pragma unroll
    for (int mt = 4; mt < 8; ++mt) aO[mt] = *(const bf16x8*)(sbO + aoff[mt]);
    asm volatile("s_waitcnt lgkmcnt(4)" ::: "memory");   // aO0-3 + bO ready
    __builtin_amdgcn_sched_barrier(0);
    __builtin_amdgcn_s_setprio(1);
#pragma unroll
    for (int mt = 0; mt < 4; ++mt)
#pragma unroll
      for (int nt = 0; nt < 4; ++nt)
        acc[mt][nt] = __builtin_amdgcn_mfma_f32_16x16x32_bf16(aO[mt], bO[nt], acc[mt][nt], 0, 0, 0);
    __builtin_amdgcn_s_setprio(0);
    asm volatile("s_waitcnt lgkmcnt(0)" ::: "memory");
    __builtin_amdgcn_sched_barrier(0);
    __builtin_amdgcn_s_setprio(1);
#pragma unroll
    for (int mt = 4; mt < 8; ++mt)
#pragma unroll
      for (int nt = 0; nt < 4; ++nt)
        acc[mt][nt] = __builtin_amdgcn_mfma_f32_16x16x32_bf16(aO[mt], bO[nt], acc[mt][nt], 0, 0, 0);
    __builtin_amdgcn_s_setprio(0);
  }
#undef STAGE

  // Epilogue: C/D layout: col = lane&15, row = quad*4 + reg (verified convention).
  const int colbase = bnBase + wn * 64;
  float c2v[4];
#pragma unroll
  for (int nt = 0; nt < 4; ++nt) c2v[nt] = c2[colbase + nt * 16 + c16];

  const int chunk = bn * 4 + wn;
#pragma unroll
  for (int mt = 0; mt < 8; ++mt) {
#pragma unroll
    for (int r = 0; r < 4; ++r) {
      float sv[4];
#pragma unroll
      for (int nt = 0; nt < 4; ++nt) sv[nt] = 2.0f * acc[mt][nt][r] - c2v[nt];
      float m = sv[0];
      int idx = colbase + c16;
#pragma unroll
      for (int nt = 1; nt < 4; ++nt) {
        if (sv[nt] > m) { m = sv[nt]; idx = colbase + nt * 16 + c16; }
      }
      float l = 0.f;
#pragma unroll
      for (int nt = 0; nt < 4; ++nt) l += __expf(sv[nt] - m);
      for (int d = 1; d < 16; d <<= 1) {
        float om = __shfl_xor(m, d, 64);
        float ol = __shfl_xor(l, d, 64);
        int oi = __shfl_xor(idx, d, 64);
        float M = fmaxf(m, om);
        l = l * __expf(m - M) + ol * __expf(om - M);
        idx = (om > m || (om == m && oi < idx)) ? oi : idx;
        m = M;
      }
      if (c16 == 0) {
        const int row = bmBase + wm * 128 + mt * 16 + quad * 4 + r;
        pm[(size_t)row * NCHUNK + chunk] = m;
        pl[(size_t)row * NCHUNK + chunk] = l;
        pidx[(size_t)row * NCHUNK + chunk] = idx;
      }
    }
  }
}

// ---------- K2: per-row combine (128 threads = 128 chunks) + fused sy dot ----------
__global__ __launch_bounds__(128) void combine_kernel(
    const float* __restrict__ pm, const float* __restrict__ pl,
    const int* __restrict__ pidx, const float* __restrict__ x,
    const float* __restrict__ cent, const float* __restrict__ c2,
    const int* __restrict__ y,
    float* __restrict__ loss_part, float* __restrict__ corr_part) {
  const int row = blockIdx.x, t = threadIdx.x;  // t = chunk id, 0..127
  const int yc = y[row];

  float m = pm[(size_t)row * NCHUNK + t];
  float l = pl[(size_t)row * NCHUNK + t];
  int idx = pidx[(size_t)row * NCHUNK + t];

  // fp32 partial dot: 8 elements per thread
  const float4* xa = (const float4*)(x + (size_t)row * KDIM) + t * 2;
  const float4* ca = (const float4*)(cent + (size_t)yc * KDIM) + t * 2;
  const float4 a0 = xa[0], a1 = xa[1], b0 = ca[0], b1 = ca[1];
  float dot = a0.x * b0.x + a0.y * b0.y + a0.z * b0.z + a0.w * b0.w
            + a1.x * b1.x + a1.y * b1.y + a1.z * b1.z + a1.w * b1.w;

  for (int d = 1; d < 64; d <<= 1) {
    const float om = __shfl_xor(m, d, 64);
    const float ol = __shfl_xor(l, d, 64);
    const int oi = __shfl_xor(idx, d, 64);
    const float od = __shfl_xor(dot, d, 64);
    const float M = fmaxf(m, om);
    l = l * __expf(m - M) + ol * __expf(om - M);
    idx = (om > m || (om == m && oi < idx)) ? oi : idx;
    m = M;
    dot += od;
  }
  __shared__ float sm[2], sl[2], sd[2];
  __shared__ int si[2];
  if ((t & 63) == 0) { sm[t >> 6] = m; sl[t >> 6] = l; si[t >> 6] = idx; sd[t >> 6] = dot; }
  __syncthreads();
  if (t == 0) {
    const float m0 = sm[0], m1 = sm[1];
    const float M = fmaxf(m0, m1);
    const float L = sl[0] * __expf(m0 - M) + sl[1] * __expf(m1 - M);
    int g;
    if (m1 > m0 || (m1 == m0 && si[1] < si[0])) g = si[1]; else g = si[0];
    const float sy = 2.0f * (sd[0] + sd[1]) - c2[yc];
    loss_part[row] = __logf(L) + M - sy;
    corr_part[row] = (g == yc) ? 1.f : 0.f;
  }
}

// ---------- K3: finalize means ----------
__global__ __launch_bounds__(256) void finalize(const float* __restrict__ loss_part,
                                                const float* __restrict__ corr_part,
                                                float* __restrict__ out) {
  const int t = threadIdx.x;
  float s0 = 0.f, s1 = 0.f;
  for (int i = t; i < MDIM; i += 256) { s0 += loss_part[i]; s1 += corr_part[i]; }
  for (int d = 32; d; d >>= 1) {
    s0 += __shfl_down(s0, d, 64);
    s1 += __shfl_down(s1, d, 64);
  }
  __shared__ float r0[4], r1[4];
  if ((t & 63) == 0) { r0[t >> 6] = s0; r1[t >> 6] = s1; }
  __syncthreads();
  if (t == 0) {
    out[0] = (r0[0] + r0[1] + r0[2] + r0[3]) * (1.0f / MDIM);
    out[1] = (r1[0] + r1[1] + r1[2] + r1[3]) * (1.0f / MDIM);
  }
}

// ---------- launch ----------
extern "C" void kernel_launch(void* const* d_in, const int* in_sizes, int n_in,
                              void* d_out, int out_size, void* d_ws, size_t ws_size,
                              hipStream_t stream) {
  const float* x = (const float*)d_in[0];
  const int* y = (const int*)d_in[1];
  const float* cent = (const float*)d_in[2];
  float* out = (float*)d_out;

  char* ws = (char*)d_ws;
  const size_t OFF_XB = 0;                                   // 4 MB
  const size_t OFF_CB = OFF_XB + (size_t)MDIM * KDIM * 2;    // 16 MB
  const size_t OFF_C2 = OFF_CB + (size_t)CDIM * KDIM * 2;    // 32 KB
  const size_t OFF_PM = OFF_C2 + (size_t)CDIM * 4;           // 1 MB
  const size_t OFF_PL = OFF_PM + (size_t)NCHUNK * MDIM * 4;  // 1 MB
  const size_t OFF_PI = OFF_PL + (size_t)NCHUNK * MDIM * 4;  // 1 MB
  const size_t OFF_LP = OFF_PI + (size_t)NCHUNK * MDIM * 4;  // 8 KB
  const size_t OFF_CP = OFF_LP + (size_t)MDIM * 4;           // 8 KB
  const size_t NEED = OFF_CP + (size_t)MDIM * 4;
  if (ws_size < NEED) return;

  unsigned short* xb = (unsigned short*)(ws + OFF_XB);
  unsigned short* cb = (unsigned short*)(ws + OFF_CB);
  float* c2 = (float*)(ws + OFF_C2);
  float* pm = (float*)(ws + OFF_PM);
  float* pl = (float*)(ws + OFF_PL);
  int* pidx = (int*)(ws + OFF_PI);
  float* loss_part = (float*)(ws + OFF_LP);
  float* corr_part = (float*)(ws + OFF_CP);

  convert_all<<<MDIM + CDIM, 256, 0, stream>>>(x, cent, xb, cb, c2);
  gemm_reduce<<<dim3(CDIM / BN, MDIM / BM), 512, 0, stream>>>(xb, cb, c2, pm, pl, pidx);
  combine_kernel<<<MDIM, 128, 0, stream>>>(pm, pl, pidx, x, cent, c2, y, loss_part, corr_part);
  finalize<<<1, 256, 0, stream>>>(loss_part, corr_part, out);
}